// Round 1
// baseline (523.647 us; speedup 1.0000x reference)
//
#include <hip/hip_runtime.h>
#include <hip/hip_bf16.h>

typedef __attribute__((ext_vector_type(8))) short short8;   // 8 bf16 = 4 VGPRs
typedef __attribute__((ext_vector_type(4))) float f32x4;
typedef unsigned int u32;
typedef unsigned short u16;

#define C_ 256
#define G_ 32
#define ND_ 18432          // D*H*W per batch
#define HW_ 2304           // 48*48
#define EPS_ 1e-5f
#define QSCALE_ 0.17677669529663687f   // 32^-0.5

static __device__ __forceinline__ u16 f2bf(float f) {
  __hip_bfloat16 h = __float2bfloat16(f);
  return __builtin_bit_cast(u16, h);
}

// ---------------- weights f32 -> bf16 ----------------
__global__ void k_convert_w(const float* __restrict__ qkv_w,
                            const float* __restrict__ proj_w,
                            u16* __restrict__ wout) {
  int i = blockIdx.x * 256 + threadIdx.x;   // grid 1024 -> 262144 exactly
  if (i < 196608) wout[i] = f2bf(qkv_w[i]);
  else            wout[i] = f2bf(proj_w[i - 196608]);
}

// ---------------- GroupNorm stats: one block per (b,g) ----------------
__global__ __launch_bounds__(1024) void k_gn_stats(const float* __restrict__ x,
                                                   float* __restrict__ stats) {
  int grp = blockIdx.x;  // b*32+g ; 8 channels * 18432 contiguous f32
  const float4* p = (const float4*)(x + (size_t)grp * 147456);
  float s1 = 0.f, s2 = 0.f;
  for (int i = threadIdx.x; i < 36864; i += 1024) {
    float4 v = p[i];
    s1 += v.x + v.y + v.z + v.w;
    s2 += v.x*v.x + v.y*v.y + v.z*v.z + v.w*v.w;
  }
  for (int off = 1; off < 64; off <<= 1) {
    s1 += __shfl_xor(s1, off, 64);
    s2 += __shfl_xor(s2, off, 64);
  }
  __shared__ float ls1[16], ls2[16];
  int wid = threadIdx.x >> 6;
  if ((threadIdx.x & 63) == 0) { ls1[wid] = s1; ls2[wid] = s2; }
  __syncthreads();
  if (threadIdx.x == 0) {
    float a = 0.f, b = 0.f;
    for (int i = 0; i < 16; i++) { a += ls1[i]; b += ls2[i]; }
    float mu  = a / 147456.0f;
    float var = b / 147456.0f - mu * mu;
    stats[grp * 2]     = mu;
    stats[grp * 2 + 1] = rsqrtf(var + EPS_);
  }
}

// ---------------- normalize + transpose: x[b][c][n] f32 -> h_t[b][n][c] bf16 ----------------
__global__ __launch_bounds__(256) void k_tnorm(const float* __restrict__ x,
                                               const float* __restrict__ stats,
                                               const float* __restrict__ nw,
                                               const float* __restrict__ nb,
                                               u16* __restrict__ h_t) {
  __shared__ u16 tl[64 * 66];   // 64n x 64c tile, +2 pad (2-way banks)
  int wg = blockIdx.x;          // 2304 = b(2) * ct(4) * nt(288)
  int nt = wg % 288; int ct = (wg / 288) & 3; int b = wg / 1152;
  int c0 = ct * 64, n0 = nt * 64;
  int tid = threadIdx.x;
#pragma unroll
  for (int p = 0; p < 4; p++) {
    int c_l = p * 16 + (tid >> 4);
    int n4  = (tid & 15) * 4;
    int cg  = c0 + c_l;
    float4 v = *(const float4*)(x + ((size_t)(b * C_ + cg)) * ND_ + n0 + n4);
    float mu = stats[(b * G_ + (cg >> 3)) * 2];
    float rs = stats[(b * G_ + (cg >> 3)) * 2 + 1];
    float w = nw[cg], bia = nb[cg];
    tl[(n4 + 0) * 66 + c_l] = f2bf((v.x - mu) * rs * w + bia);
    tl[(n4 + 1) * 66 + c_l] = f2bf((v.y - mu) * rs * w + bia);
    tl[(n4 + 2) * 66 + c_l] = f2bf((v.z - mu) * rs * w + bia);
    tl[(n4 + 3) * 66 + c_l] = f2bf((v.w - mu) * rs * w + bia);
  }
  __syncthreads();
#pragma unroll
  for (int p = 0; p < 2; p++) {
    int idx = p * 256 + tid;       // 512 chunks of 8 bf16
    int n_l = idx >> 3, c8 = idx & 7;
    const u32* s = (const u32*)((const char*)tl + n_l * 132 + c8 * 16);
    uint4 vv; vv.x = s[0]; vv.y = s[1]; vv.z = s[2]; vv.w = s[3];
    *(uint4*)(h_t + ((size_t)(b * ND_ + n0 + n_l)) * C_ + c0 + c8 * 8) = vv;
  }
}

// ---------------- QK GEMM (swapped: A=H [n x c], B=W^T [c x o]) ----------------
// grid 2304 = b(2) * ot(4: o0=0..384 step128) * nt(288)
__global__ __launch_bounds__(256) void k_qk(const u16* __restrict__ h_t,
                                            const u16* __restrict__ w_qkv,
                                            const float* __restrict__ qkv_b,
                                            u16* __restrict__ q_ws,
                                            u16* __restrict__ k_ws) {
  int wg = blockIdx.x;
  int nt = wg % 288; int ot = (wg / 288) & 3; int b = wg / 1152;
  int n0 = nt * 64, o0 = ot * 128;
  int lane = threadIdx.x & 63; int w = threadIdx.x >> 6;
  int g = lane >> 4, lid = lane & 15;
  int n_w = n0 + w * 16;
  f32x4 acc[8];
#pragma unroll
  for (int t = 0; t < 8; t++) acc[t] = (f32x4){0.f, 0.f, 0.f, 0.f};
  const short8* Ab = (const short8*)(h_t + ((size_t)(b * ND_ + n_w + lid)) * C_ + g * 8);
#pragma unroll
  for (int ks = 0; ks < 8; ks++) {
    short8 a = Ab[ks * 4];
#pragma unroll
    for (int t = 0; t < 8; t++) {
      short8 bf = *(const short8*)(w_qkv + ((size_t)(o0 + t * 16 + lid)) * C_ + ks * 32 + g * 8);
      acc[t] = __builtin_amdgcn_mfma_f32_16x16x32_bf16(a, bf, acc[t], 0, 0, 0);
    }
  }
#pragma unroll
  for (int t = 0; t < 8; t++) {
    int o_t = o0 + t * 16;
    float bias = qkv_b[o_t + lid];
    bool isq = (o_t < 256);
    float mul = isq ? QSCALE_ : 1.0f;
    u16* dst = isq ? q_ws : k_ws;
    int oc = isq ? (o_t + lid) : (o_t - 256 + lid);
#pragma unroll
    for (int r = 0; r < 4; r++) {
      int n_idx = n_w + g * 4 + r;
      dst[((size_t)(b * ND_ + n_idx)) * C_ + oc] = f2bf((acc[t][r] + bias) * mul);
    }
  }
}

// ---------------- V GEMM (normal: A=W [o x c], B=H^T) -> v channel-major [b][o][n] ----------------
// grid 1152 = b(2) * ot(4: 64 wide) * nt(144: 128 wide)
__global__ __launch_bounds__(256) void k_v(const u16* __restrict__ h_t,
                                           const u16* __restrict__ w_qkv,
                                           const float* __restrict__ qkv_b,
                                           u16* __restrict__ v_ws) {
  int wg = blockIdx.x;
  int nt = wg % 144; int ot = (wg / 144) & 3; int b = wg / 576;
  int n0 = nt * 128, o0 = ot * 64;
  int lane = threadIdx.x & 63; int w = threadIdx.x >> 6;
  int g = lane >> 4, lid = lane & 15;
  int o_w = o0 + w * 16;
  f32x4 acc[8];
#pragma unroll
  for (int t = 0; t < 8; t++) acc[t] = (f32x4){0.f, 0.f, 0.f, 0.f};
  const short8* Ab = (const short8*)(w_qkv + ((size_t)(512 + o_w + lid)) * C_ + g * 8);
#pragma unroll
  for (int ks = 0; ks < 8; ks++) {
    short8 a = Ab[ks * 4];
#pragma unroll
    for (int t = 0; t < 8; t++) {
      short8 bf = *(const short8*)(h_t + ((size_t)(b * ND_ + n0 + t * 16 + lid)) * C_ + ks * 32 + g * 8);
      acc[t] = __builtin_amdgcn_mfma_f32_16x16x32_bf16(a, bf, acc[t], 0, 0, 0);
    }
  }
#pragma unroll
  for (int t = 0; t < 8; t++) {
#pragma unroll
    for (int r = 0; r < 4; r++) {
      int o = o_w + g * 4 + r;
      int n = n0 + t * 16 + lid;
      v_ws[((size_t)(b * C_ + o)) * ND_ + n] = f2bf(acc[t][r] + qkv_b[512 + o]);
    }
  }
}

// ---------------- fused attention per (b,d) slice ----------------
// grid 576 = slice(16) * qt(36) ; 4 waves * 16 q each
__global__ __launch_bounds__(256, 2) void k_attn(const u16* __restrict__ q_ws,
                                                 const u16* __restrict__ k_ws,
                                                 const u16* __restrict__ v_ws,
                                                 u16* __restrict__ ao) {
  __shared__ __align__(16) unsigned char lds[62464];
  // K: [48 rows][512B] XOR-swizzled        @ 0      (24576B)
  // V: [256 rows][112B] (48 real + pad)    @ 24576  (28672B)
  // P: per-wave [16 rows][144B] (72 cols)  @ 53248  (9216B)
  int wg = blockIdx.x;
  int qt = wg % 36; int slice = wg / 36;
  int b = slice >> 3, d = slice & 7;
  int q0 = qt * 64;
  int tid = threadIdx.x; int lane = tid & 63; int w = tid >> 6;
  int g = lane >> 4, lid = lane & 15;

  for (int i = tid; i < 9472; i += 256) ((u32*)(lds + 24576))[i] = 0;  // zero V+P
  __syncthreads();

  short8 qf[8];
  {
    const short8* qb = (const short8*)(q_ws + ((size_t)(b * ND_ + d * HW_ + q0 + w * 16 + lid)) * C_ + g * 8);
#pragma unroll
    for (int ks = 0; ks < 8; ks++) qf[ks] = qb[ks * 4];
  }
  f32x4 acc[16];
#pragma unroll
  for (int i = 0; i < 16; i++) acc[i] = (f32x4){0.f, 0.f, 0.f, 0.f};

  const unsigned char* kbase = (const unsigned char*)(k_ws + ((size_t)(b * ND_ + d * HW_)) * C_);
  const u16* vbase = v_ws + (size_t)(b * C_) * ND_ + d * HW_;
  unsigned char* klds = lds;
  unsigned char* vlds = lds + 24576;
  unsigned char* plds = lds + 53248 + w * 2304;

  for (int kt = 0; kt < 48; kt++) {
    int sk0 = kt * 48;
    { // stage K: 24KB contiguous, swizzled write
      const uint4* src = (const uint4*)(kbase + (size_t)sk0 * 512);
#pragma unroll
      for (int i = 0; i < 6; i++) {
        int m = tid + i * 256;
        int row = m >> 5, col = m & 31;
        *(uint4*)(klds + row * 512 + ((col * 16) ^ ((row & 7) << 4))) = src[m];
      }
    }
    { // stage V: thread = channel row, 96B each
      const uint4* src = (const uint4*)(vbase + (size_t)tid * ND_ + sk0);
      uint4* dst = (uint4*)(vlds + tid * 112);
#pragma unroll
      for (int i = 0; i < 6; i++) dst[i] = src[i];
    }
    __syncthreads();

    f32x4 sc[3];
#pragma unroll
    for (int t = 0; t < 3; t++) sc[t] = (f32x4){0.f, 0.f, 0.f, 0.f};
#pragma unroll
    for (int ks = 0; ks < 8; ks++) {
#pragma unroll
      for (int t = 0; t < 3; t++) {
        int row = t * 16 + lid;
        short8 kf = *(const short8*)(klds + row * 512 + ((ks * 64 + g * 16) ^ ((row & 7) << 4)));
        sc[t] = __builtin_amdgcn_mfma_f32_16x16x32_bf16(qf[ks], kf, sc[t], 0, 0, 0);
      }
    }
    // exact softmax over the 48 keys of this H' group, per query row
#pragma unroll
    for (int r = 0; r < 4; r++) {
      float v0 = sc[0][r], v1 = sc[1][r], v2 = sc[2][r];
      float m = fmaxf(v0, fmaxf(v1, v2));
      for (int off = 1; off < 16; off <<= 1) m = fmaxf(m, __shfl_xor(m, off, 64));
      float e0 = __expf(v0 - m), e1 = __expf(v1 - m), e2 = __expf(v2 - m);
      float z = e0 + e1 + e2;
      for (int off = 1; off < 16; off <<= 1) z += __shfl_xor(z, off, 64);
      float inv = 1.0f / z;
      int q = g * 4 + r;
      u16* pr = (u16*)(plds + q * 144) + lid;
      pr[0]  = f2bf(e0 * inv);
      pr[16] = f2bf(e1 * inv);
      pr[32] = f2bf(e2 * inv);
    }
    __syncthreads();
    // PV: A = P (LDS), B = V (LDS, channel-major rows)
#pragma unroll
    for (int ks = 0; ks < 2; ks++) {
      short8 pf = *(const short8*)(plds + lid * 144 + ks * 64 + g * 16);
#pragma unroll
      for (int ct = 0; ct < 16; ct++) {
        short8 vf = *(const short8*)(vlds + (ct * 16 + lid) * 112 + ks * 64 + g * 16);
        acc[ct] = __builtin_amdgcn_mfma_f32_16x16x32_bf16(pf, vf, acc[ct], 0, 0, 0);
      }
    }
    __syncthreads();
  }
#pragma unroll
  for (int ct = 0; ct < 16; ct++) {
#pragma unroll
    for (int r = 0; r < 4; r++) {
      int q = q0 + w * 16 + g * 4 + r;
      ao[((size_t)(b * ND_ + d * HW_ + q)) * C_ + ct * 16 + lid] = f2bf(acc[ct][r]);
    }
  }
}

// ---------------- proj + bias + residual -> d_out f32 channel-major ----------------
// grid 1152 = b(2) * ot(4: 64 wide) * nt(144: 128 wide)
__global__ __launch_bounds__(256) void k_proj(const u16* __restrict__ ao,
                                              const u16* __restrict__ w_p,
                                              const float* __restrict__ proj_b,
                                              const float* __restrict__ x,
                                              float* __restrict__ out) {
  int wg = blockIdx.x;
  int nt = wg % 144; int ot = (wg / 144) & 3; int b = wg / 576;
  int n0 = nt * 128, o0 = ot * 64;
  int lane = threadIdx.x & 63; int w = threadIdx.x >> 6;
  int g = lane >> 4, lid = lane & 15;
  int o_w = o0 + w * 16;
  f32x4 acc[8];
#pragma unroll
  for (int t = 0; t < 8; t++) acc[t] = (f32x4){0.f, 0.f, 0.f, 0.f};
  const short8* Ab = (const short8*)(w_p + ((size_t)(o_w + lid)) * C_ + g * 8);
#pragma unroll
  for (int ks = 0; ks < 8; ks++) {
    short8 a = Ab[ks * 4];
#pragma unroll
    for (int t = 0; t < 8; t++) {
      short8 bf = *(const short8*)(ao + ((size_t)(b * ND_ + n0 + t * 16 + lid)) * C_ + ks * 32 + g * 8);
      acc[t] = __builtin_amdgcn_mfma_f32_16x16x32_bf16(a, bf, acc[t], 0, 0, 0);
    }
  }
#pragma unroll
  for (int t = 0; t < 8; t++) {
#pragma unroll
    for (int r = 0; r < 4; r++) {
      int o = o_w + g * 4 + r;
      size_t off = ((size_t)(b * C_ + o)) * ND_ + n0 + t * 16 + lid;
      out[off] = acc[t][r] + proj_b[o] + x[off];
    }
  }
}

extern "C" void kernel_launch(void* const* d_in, const int* in_sizes, int n_in,
                              void* d_out, int out_size, void* d_ws, size_t ws_size,
                              hipStream_t stream) {
  const float* x      = (const float*)d_in[0];
  const float* norm_w = (const float*)d_in[1];
  const float* norm_b = (const float*)d_in[2];
  const float* qkv_w  = (const float*)d_in[3];
  const float* qkv_b  = (const float*)d_in[4];
  const float* proj_w = (const float*)d_in[5];
  const float* proj_b = (const float*)d_in[6];

  char* ws = (char*)d_ws;
  // layout: stats(1KB) | w_qkv bf16 (384KB) | w_p bf16 (128KB) | h_t (18MB, reused as ao) | q | k | v
  float* stats = (float*)ws;
  u16* w_qkv = (u16*)(ws + 1024);
  u16* w_p   = (u16*)(ws + 1024 + 393216);
  u16* h_t   = (u16*)(ws + 525312);
  u16* q_ws  = h_t + 9437184;
  u16* k_ws  = q_ws + 9437184;
  u16* v_ws  = k_ws + 9437184;
  u16* ao    = h_t;  // alias: h_t dead after k_v, ao produced by k_attn
  float* out = (float*)d_out;

  if (ws_size < (size_t)525312 + 4ull * 9437184ull * 2ull) return;  // need ~76MB

  hipLaunchKernelGGL(k_convert_w, dim3(1024), dim3(256), 0, stream, qkv_w, proj_w, w_qkv);
  hipLaunchKernelGGL(k_gn_stats,  dim3(64),   dim3(1024), 0, stream, x, stats);
  hipLaunchKernelGGL(k_tnorm,     dim3(2304), dim3(256), 0, stream, x, stats, norm_w, norm_b, h_t);
  hipLaunchKernelGGL(k_qk,        dim3(2304), dim3(256), 0, stream, h_t, w_qkv, qkv_b, q_ws, k_ws);
  hipLaunchKernelGGL(k_v,         dim3(1152), dim3(256), 0, stream, h_t, w_qkv, qkv_b, v_ws);
  hipLaunchKernelGGL(k_attn,      dim3(576),  dim3(256), 0, stream, q_ws, k_ws, v_ws, ao);
  hipLaunchKernelGGL(k_proj,      dim3(1152), dim3(256), 0, stream, ao, w_p, proj_b, x, out);
}